// Round 1
// baseline (5554.431 us; speedup 1.0000x reference)
//
#include <hip/hip_runtime.h>
#include <hip/hip_bf16.h>
#include <stdint.h>

// ---------------------------------------------------------------------------
// CrossEntropyLoss: loss = lw/chunk * sum_rows( logsumexp_v(h_i . W_v) - h_i . W_label )
// M=8192, K=2048, V=128000.
// GEMM+exp+rowsum uses the 256x256 8-phase schedule (T1+T2+T3+T4+T5):
//   8 waves (512 thr), BK=64, 128 KiB LDS double-buffer, full XOR bank swizzle,
//   counted vmcnt(6) at tile boundaries only, setprio around MFMA clusters.
// ---------------------------------------------------------------------------

typedef __attribute__((ext_vector_type(8))) __bf16 bf16x8;
typedef __attribute__((ext_vector_type(4))) float f32x4;

#define BK 64

__device__ __forceinline__ unsigned int pack2_bf16_rne(float lo, float hi) {
    unsigned int ulo = __float_as_uint(lo);
    ulo += 0x7fffu + ((ulo >> 16) & 1u);
    unsigned int uhi = __float_as_uint(hi);
    uhi += 0x7fffu + ((uhi >> 16) & 1u);
    return (ulo >> 16) | (uhi & 0xffff0000u);
}

// Convert n8*8 floats -> bf16 (packed), 8 elements per thread, 16B stores.
__global__ void cvt_f32_bf16(const float* __restrict__ src,
                             unsigned int* __restrict__ dst, long long n8) {
    long long i = (long long)blockIdx.x * blockDim.x + threadIdx.x;
    if (i >= n8) return;
    const float4* s4 = (const float4*)src;
    float4 a = s4[i * 2];
    float4 b = s4[i * 2 + 1];
    uint4 o;
    o.x = pack2_bf16_rne(a.x, a.y);
    o.y = pack2_bf16_rne(a.z, a.w);
    o.z = pack2_bf16_rne(b.x, b.y);
    o.w = pack2_bf16_rne(b.z, b.w);
    ((uint4*)dst)[i] = o;
}

// Stage one half-tile chunk for this wave: 2 x (64 lanes x 16B) global_load_lds.
// LDS dest is LINEAR (wave-uniform base + lane*16); the XOR swizzle is applied
// to the GLOBAL source column (rule #21: linear dest + inverse-swz source).
// Swizzle: within a row, 16B-granule g holds global granule g ^ (row&7).
__device__ __forceinline__ void stage_half(const unsigned short* __restrict__ G,
                                           int K, int kt,
                                           unsigned short* lds, int baseElems,
                                           int h, int w, int lane) {
    const int rl = h * 128 + w * 16 + (lane >> 3);          // row within 256-row tile
    const int csw = ((lane & 7) ^ (lane >> 3)) * 8;         // swizzled source col (elems)
#pragma unroll
    for (int inst = 0; inst < 2; ++inst) {
        __builtin_amdgcn_global_load_lds(
            (__attribute__((address_space(1))) void*)(G + (size_t)(rl + inst * 8) * K + kt + csw),
            (__attribute__((address_space(3))) void*)(lds + baseElems + w * 1024 + inst * 512),
            16, 0, 0);
    }
}

#define FULL_BAR()  asm volatile("" ::: "memory"); \
                    __builtin_amdgcn_s_barrier();  \
                    asm volatile("" ::: "memory")

// ---------------------------------------------------------------------------
// 256x256 tile, BK=64, 8 waves as 2x4 within each 128x128 quadrant.
// LDS layout (elements): buf p at p*32768; A tile [256][64] at +0,
// B tile [256][64] at +16384. Half h = rows h*128..h*128+127 (8192 elems).
// blockIdx -> (bm, bn) via bijective XCD swizzle; consecutive wg share bn.
// ---------------------------------------------------------------------------
__global__ __launch_bounds__(512, 2) void gemm_sumexp(
    const unsigned short* __restrict__ A,
    const unsigned short* __restrict__ Bs,
    float* __restrict__ rowsum,
    int K, int Mtiles)
{
    extern __shared__ unsigned short lds[];

    const int tid = threadIdx.x;
    const int lane = tid & 63;
    const int w = tid >> 6;          // 0..7
    const int wm2 = w >> 2;          // 0..1 : 64-row half within quadrant
    const int wn2 = w & 3;           // 0..3 : 32-col strip within quadrant
    const int l15 = lane & 15;
    const int l7 = lane & 7;
    const int kq = lane >> 4;        // 0..3

    // T1: bijective XCD-aware remap (m204)
    const unsigned nwg = gridDim.x;
    const unsigned q8 = nwg >> 3, r8 = nwg & 7;
    const unsigned xcd = blockIdx.x & 7, lid = blockIdx.x >> 3;
    const unsigned wg = (xcd < r8) ? (xcd * (q8 + 1) + lid)
                                   : (r8 * (q8 + 1) + (xcd - r8) * q8 + lid);
    const int bm = (int)(wg % (unsigned)Mtiles);
    const int bn = (int)(wg / (unsigned)Mtiles);

    const unsigned short* gA = A + (size_t)bm * 256 * K;
    const unsigned short* gB = Bs + (size_t)bn * 256 * K;

    const int NT = K / BK;

    f32x4 zero = {0.f, 0.f, 0.f, 0.f};
    f32x4 acc[2][2][4][2];
#pragma unroll
    for (int qa = 0; qa < 2; ++qa)
#pragma unroll
        for (int qb = 0; qb < 2; ++qb)
#pragma unroll
            for (int mf = 0; mf < 4; ++mf)
#pragma unroll
                for (int nf = 0; nf < 2; ++nf) acc[qa][qb][mf][nf] = zero;

    // ---- prologue: tile0 (Ah0,Bh0,Bh1,Ah1) -> buf0 ; tile1 (Ah0,Bh0,Bh1) -> buf1
    stage_half(gA, K, 0, lds, 0,             0, w, lane);
    stage_half(gB, K, 0, lds, 16384,         0, w, lane);
    stage_half(gB, K, 0, lds, 16384 + 8192,  1, w, lane);
    stage_half(gA, K, 0, lds, 8192,          1, w, lane);
    if (NT > 1) {
        stage_half(gA, K, BK, lds, 32768,            0, w, lane);
        stage_half(gB, K, BK, lds, 32768 + 16384,    0, w, lane);
        stage_half(gB, K, BK, lds, 32768 + 24576,    1, w, lane);
        asm volatile("s_waitcnt vmcnt(6)" ::: "memory");
    } else {
        asm volatile("s_waitcnt vmcnt(0)" ::: "memory");
    }
    FULL_BAR();

    bf16x8 af[4][2];        // current qa-half A frags (reloaded at ph2)
    bf16x8 bf[2][2][2];     // [qb][nf][kk]

    int p = 0;
    for (int tt = 0; tt < NT; ++tt, p ^= 1) {
        const int pb = p * 32768;
        const int pnb = (p ^ 1) * 32768;
        const int ktA = (tt + 1) * BK;
        const int ktB = (tt + 2) * BK;

        // ---------------- ph0 : quadrant (0,0) ----------------
#pragma unroll
        for (int mf = 0; mf < 4; ++mf)
#pragma unroll
            for (int kk = 0; kk < 2; ++kk) {
                const int ra = wm2 * 64 + mf * 16 + l15;              // qa=0
                const int col = ((kk * 4 + kq) ^ l7) * 8;
                af[mf][kk] = *(const bf16x8*)&lds[pb + ra * 64 + col];
            }
#pragma unroll
        for (int nf = 0; nf < 2; ++nf)
#pragma unroll
            for (int kk = 0; kk < 2; ++kk) {
                const int rb = wn2 * 32 + nf * 16 + l15;              // qb=0
                const int col = ((kk * 4 + kq) ^ l7) * 8;
                bf[0][nf][kk] = *(const bf16x8*)&lds[pb + 16384 + rb * 64 + col];
            }
        if (tt + 1 < NT) stage_half(gA, K, ktA, lds, pnb + 8192, 1, w, lane);   // (t+1).Ah1
        FULL_BAR();
        __builtin_amdgcn_s_setprio(1);
#pragma unroll
        for (int kk = 0; kk < 2; ++kk)
#pragma unroll
            for (int mf = 0; mf < 4; ++mf)
#pragma unroll
                for (int nf = 0; nf < 2; ++nf)
                    acc[0][0][mf][nf] = __builtin_amdgcn_mfma_f32_16x16x32_bf16(
                        af[mf][kk], bf[0][nf][kk], acc[0][0][mf][nf], 0, 0, 0);
        __builtin_amdgcn_s_setprio(0);
        FULL_BAR();

        // ---------------- ph1 : quadrant (0,1) ----------------
#pragma unroll
        for (int nf = 0; nf < 2; ++nf)
#pragma unroll
            for (int kk = 0; kk < 2; ++kk) {
                const int rb = 128 + wn2 * 32 + nf * 16 + l15;        // qb=1
                const int col = ((kk * 4 + kq) ^ l7) * 8;
                bf[1][nf][kk] = *(const bf16x8*)&lds[pb + 16384 + rb * 64 + col];
            }
        if (tt + 2 < NT) stage_half(gA, K, ktB, lds, pb, 0, w, lane);           // (t+2).Ah0
        FULL_BAR();
        __builtin_amdgcn_s_setprio(1);
#pragma unroll
        for (int kk = 0; kk < 2; ++kk)
#pragma unroll
            for (int mf = 0; mf < 4; ++mf)
#pragma unroll
                for (int nf = 0; nf < 2; ++nf)
                    acc[0][1][mf][nf] = __builtin_amdgcn_mfma_f32_16x16x32_bf16(
                        af[mf][kk], bf[1][nf][kk], acc[0][1][mf][nf], 0, 0, 0);
        __builtin_amdgcn_s_setprio(0);
        FULL_BAR();

        // ---------------- ph2 : quadrant (1,0) ----------------
#pragma unroll
        for (int mf = 0; mf < 4; ++mf)
#pragma unroll
            for (int kk = 0; kk < 2; ++kk) {
                const int ra = 128 + wm2 * 64 + mf * 16 + l15;        // qa=1
                const int col = ((kk * 4 + kq) ^ l7) * 8;
                af[mf][kk] = *(const bf16x8*)&lds[pb + ra * 64 + col];
            }
        if (tt + 2 < NT) stage_half(gB, K, ktB, lds, pb + 16384, 0, w, lane);   // (t+2).Bh0
        FULL_BAR();
        __builtin_amdgcn_s_setprio(1);
#pragma unroll
        for (int kk = 0; kk < 2; ++kk)
#pragma unroll
            for (int mf = 0; mf < 4; ++mf)
#pragma unroll
                for (int nf = 0; nf < 2; ++nf)
                    acc[1][0][mf][nf] = __builtin_amdgcn_mfma_f32_16x16x32_bf16(
                        af[mf][kk], bf[0][nf][kk], acc[1][0][mf][nf], 0, 0, 0);
        __builtin_amdgcn_s_setprio(0);
        FULL_BAR();

        // ---------------- ph3 : quadrant (1,1) ----------------
        if (tt + 2 < NT) stage_half(gB, K, ktB, lds, pb + 24576, 1, w, lane);   // (t+2).Bh1
        FULL_BAR();
        __builtin_amdgcn_s_setprio(1);
#pragma unroll
        for (int kk = 0; kk < 2; ++kk)
#pragma unroll
            for (int mf = 0; mf < 4; ++mf)
#pragma unroll
                for (int nf = 0; nf < 2; ++nf)
                    acc[1][1][mf][nf] = __builtin_amdgcn_mfma_f32_16x16x32_bf16(
                        af[mf][kk], bf[1][nf][kk], acc[1][1][mf][nf], 0, 0, 0);
        __builtin_amdgcn_s_setprio(0);
        // tile boundary: counted drain — keep next tile's 3 chunks in flight
        if (tt + 2 < NT) {
            asm volatile("s_waitcnt vmcnt(6)" ::: "memory");
        } else if (tt + 1 < NT) {
            asm volatile("s_waitcnt vmcnt(0)" ::: "memory");
        }
        FULL_BAR();
    }

    // ---- epilogue: sum exp over this block's 256 columns per row, atomic into rowsum.
    // C/D: row = qa*128 + wm2*64 + mf*16 + (lane>>4)*4 + j ; col = qb*128 + wn2*32 + nf*16 + (lane&15)
#pragma unroll
    for (int qa = 0; qa < 2; ++qa)
#pragma unroll
        for (int mf = 0; mf < 4; ++mf)
#pragma unroll
            for (int j = 0; j < 4; ++j) {
                float v = __expf(acc[qa][0][mf][0][j]) + __expf(acc[qa][0][mf][1][j])
                        + __expf(acc[qa][1][mf][0][j]) + __expf(acc[qa][1][mf][1][j]);
#pragma unroll
                for (int off = 1; off < 16; off <<= 1) v += __shfl_xor(v, off, 64);
                if (l15 == 0) {
                    const int row = bm * 256 + qa * 128 + wm2 * 64 + mf * 16 + kq * 4 + j;
                    atomicAdd(&rowsum[row], v);
                }
            }
}

// Exact f32 target logit: one block per row.
__global__ void tgt_kernel(const float* __restrict__ h, const float* __restrict__ W,
                           const int* __restrict__ labels, float* __restrict__ tgt, int D) {
    const int row = blockIdx.x;
    const int lab = labels[row];
    const float4* hr = (const float4*)(h + (size_t)row * D);
    const float4* wr = (const float4*)(W + (size_t)lab * D);
    float p = 0.f;
    for (int i = threadIdx.x; i < D / 4; i += blockDim.x) {
        float4 a = hr[i], b = wr[i];
        p += a.x * b.x + a.y * b.y + a.z * b.z + a.w * b.w;
    }
#pragma unroll
    for (int off = 32; off; off >>= 1) p += __shfl_xor(p, off, 64);
    __shared__ float red[4];
    if ((threadIdx.x & 63) == 0) red[threadIdx.x >> 6] = p;
    __syncthreads();
    if (threadIdx.x == 0) tgt[row] = red[0] + red[1] + red[2] + red[3];
}

__global__ void final_kernel(const float* __restrict__ rowsum, const float* __restrict__ tgt,
                             const float* __restrict__ lw, const int* __restrict__ csz,
                             float* __restrict__ out, int M) {
    float p = 0.f;
    for (int i = threadIdx.x; i < M; i += blockDim.x)
        p += logf(rowsum[i]) - tgt[i];
#pragma unroll
    for (int off = 32; off; off >>= 1) p += __shfl_xor(p, off, 64);
    __shared__ float red[4];
    if ((threadIdx.x & 63) == 0) red[threadIdx.x >> 6] = p;
    __syncthreads();
    if (threadIdx.x == 0) out[0] = lw[0] * (red[0] + red[1] + red[2] + red[3]) / (float)csz[0];
}

extern "C" void kernel_launch(void* const* d_in, const int* in_sizes, int n_in,
                              void* d_out, int out_size, void* d_ws, size_t ws_size,
                              hipStream_t stream) {
    const float* h = (const float*)d_in[0];       // [M][D] f32
    const float* W = (const float*)d_in[1];       // [V][D] f32
    const int* labels = (const int*)d_in[2];      // [M]
    const float* lw = (const float*)d_in[3];      // scalar
    const int* csz = (const int*)d_in[4];         // scalar (1024)

    const int M = in_sizes[2];                    // 8192
    const int D = in_sizes[0] / M;                // 2048
    const int V = in_sizes[1] / D;                // 128000
    const int Mtiles = M / 256;                   // 32
    const int total_vtiles = V / 256;             // 500

    static int attr_set = 0;
    if (!attr_set) {
        hipFuncSetAttribute((const void*)gemm_sumexp,
                            hipFuncAttributeMaxDynamicSharedMemorySize, 131072);
        attr_set = 1;
    }

    char* ws = (char*)d_ws;
    float* rowsum = (float*)ws;                                   // M floats
    float* tgt = (float*)(ws + (size_t)M * 4);                    // M floats
    unsigned short* Abf = (unsigned short*)(ws + (size_t)M * 8);  // M*D bf16
    size_t Abytes = (size_t)M * D * 2;
    unsigned short* Wbf = (unsigned short*)(ws + (size_t)M * 8 + Abytes);

    const size_t tile_bytes = (size_t)256 * D * 2;  // 1 MB per vocab tile
    long long avail = (long long)ws_size - (long long)((size_t)M * 8 + Abytes);
    int slice_tiles = (avail > 0) ? (int)(avail / (long long)tile_bytes) : 1;
    if (slice_tiles > total_vtiles) slice_tiles = total_vtiles;
    if (slice_tiles < 1) slice_tiles = 1;

    // zero rowsum + tgt
    hipMemsetAsync(rowsum, 0, (size_t)M * 8, stream);

    // convert hidden -> bf16
    long long nA8 = (long long)M * D / 8;
    cvt_f32_bf16<<<(unsigned)((nA8 + 255) / 256), 256, 0, stream>>>(h, (unsigned int*)Abf, nA8);

    // per-slice: convert W slice -> bf16, then GEMM+exp-accumulate
    for (int t0 = 0; t0 < total_vtiles; t0 += slice_tiles) {
        int nt = slice_tiles;
        if (t0 + nt > total_vtiles) nt = total_vtiles - t0;
        long long nW8 = (long long)nt * 256 * D / 8;
        cvt_f32_bf16<<<(unsigned)((nW8 + 255) / 256), 256, 0, stream>>>(
            W + (size_t)t0 * 256 * D, (unsigned int*)Wbf, nW8);
        gemm_sumexp<<<(unsigned)(Mtiles * nt), 512, 131072, stream>>>(Abf, Wbf, rowsum, D, Mtiles);
    }

    tgt_kernel<<<M, 256, 0, stream>>>(h, W, labels, tgt, D);
    final_kernel<<<1, 256, 0, stream>>>(rowsum, tgt, lw, csz, (float*)d_out, M);
}